// Round 1
// baseline (165.156 us; speedup 1.0000x reference)
//
#include <hip/hip_runtime.h>
#include <hip/hip_bf16.h>
#include <stdint.h>

typedef __bf16 bf16x8 __attribute__((ext_vector_type(8)));
typedef float  f32x4  __attribute__((ext_vector_type(4)));

union U16x8 { bf16x8 v; unsigned short s[8]; uint4 q; };

__device__ inline unsigned short f2bf(float f) {
  union { float f; unsigned int u; } x; x.f = f;
  unsigned int r = x.u + 0x7FFFu + ((x.u >> 16) & 1u);
  return (unsigned short)(r >> 16);
}
__device__ inline float bf2f(unsigned short u) {
  union { unsigned int u; float f; } x; x.u = ((unsigned int)u) << 16; return x.f;
}

// ---------------------------------------------------------------- K0: weights -> bf16
__global__ void k_prep_w(const float* si_w, const float* fi_w, const float* gi_w,
                         unsigned short* wbs, unsigned short* wbf, unsigned short* wbg) {
  for (int i = threadIdx.x; i < 4096; i += 256) {
    wbs[i] = f2bf(si_w[i]);
    wbf[i] = f2bf(fi_w[i]);
    wbg[i] = f2bf(gi_w[i]);
  }
}

// ---------------------------------------------------------------- Ksx: exact spatial sums of x
__global__ __launch_bounds__(256) void k_sx(const float* stu, const float* tea, float* Sx) {
  int bid = blockIdx.x;               // 512 = br(2) * ba(4) * c(64)
  int c = bid & 63, ba = (bid >> 6) & 3, br = bid >> 8;
  const float* xp = (br ? tea : stu) + (size_t)(ba * 64 + c) * 4096;
  int t = threadIdx.x;
  float acc = 0.f;
  const float4* p4 = (const float4*)xp;
  for (int i = t; i < 1024; i += 256) {
    float4 v = p4[i];
    acc += (v.x + v.y) + (v.z + v.w);
  }
  __shared__ float red[256];
  red[t] = acc; __syncthreads();
  for (int s = 128; s > 0; s >>= 1) { if (t < s) red[t] += red[t + s]; __syncthreads(); }
  if (t == 0) Sx[bid] = red[0];       // bid == (br*4+ba)*64 + c
}

// ---------------------------------------------------------------- K1: projections -> sT,fT,gT (bf16, [n][c])
__global__ __launch_bounds__(256) void k_proj(
    const float* stu, const float* tea,
    const unsigned short* wbs, const unsigned short* wbf, const unsigned short* wbg,
    const float* si_b, const float* fi_b, const float* gi_b,
    unsigned short* sT, unsigned short* fT, unsigned short* gT) {
  int bid = blockIdx.x;               // 256 = br_ba(8) * nt(32)
  int br_ba = bid & 7;
  int nt = bid >> 3;
  int br = br_ba >> 2, ba = br_ba & 3;
  const float* x = (br ? tea : stu) + (size_t)ba * 64 * 4096;
  int t = threadIdx.x;
  int wid = t >> 6, l = t & 63, g = l >> 4, lr = l & 15;
  int n0 = nt * 128 + wid * 32;

  // A fragments: rows n (output rows), k = channel c
  U16x8 afr[2][2];
  #pragma unroll
  for (int rf = 0; rf < 2; ++rf) {
    int n = n0 + rf * 16 + lr;
    #pragma unroll
    for (int kh = 0; kh < 2; ++kh) {
      #pragma unroll
      for (int j = 0; j < 8; ++j) {
        int c = kh * 32 + g * 8 + j;
        afr[rf][kh].s[j] = f2bf(x[(size_t)c * 4096 + n]);
      }
    }
  }

  size_t obase = (size_t)br_ba * 4096 * 64;
  auto proj_one = [&](const unsigned short* wb, const float* bias, unsigned short* op) {
    U16x8 bfr[4][2];
    #pragma unroll
    for (int cf = 0; cf < 4; ++cf) {
      int d = cf * 16 + lr;
      #pragma unroll
      for (int kh = 0; kh < 2; ++kh)
        bfr[cf][kh].q = *(const uint4*)(wb + d * 64 + kh * 32 + g * 8);
    }
    f32x4 acc[2][4];
    #pragma unroll
    for (int rf = 0; rf < 2; ++rf)
      #pragma unroll
      for (int cf = 0; cf < 4; ++cf)
        acc[rf][cf] = (f32x4){0.f, 0.f, 0.f, 0.f};
    #pragma unroll
    for (int kh = 0; kh < 2; ++kh)
      #pragma unroll
      for (int rf = 0; rf < 2; ++rf)
        #pragma unroll
        for (int cf = 0; cf < 4; ++cf)
          acc[rf][cf] = __builtin_amdgcn_mfma_f32_16x16x32_bf16(
              afr[rf][kh].v, bfr[cf][kh].v, acc[rf][cf], 0, 0, 0);
    #pragma unroll
    for (int cf = 0; cf < 4; ++cf) {
      float bias_v = bias[cf * 16 + lr];
      #pragma unroll
      for (int rf = 0; rf < 2; ++rf) {
        #pragma unroll
        for (int r = 0; r < 4; ++r) {
          int n = n0 + rf * 16 + g * 4 + r;
          op[(size_t)n * 64 + cf * 16 + lr] = f2bf(acc[rf][cf][r] + bias_v);
        }
      }
    }
  };
  proj_one(wbs, si_b, sT + obase);
  proj_one(wbf, fi_b, fT + obase);
  proj_one(wbg, gi_b, gT + obase);
}

// ---------------------------------------------------------------- K2: Fm tiles -> per-(n, m-block) softmax stats
__global__ __launch_bounds__(256) void k_scores(
    const unsigned short* sT, const unsigned short* fT,
    float* stats_mx, float* stats_sm) {
  int bid = blockIdx.x;               // 8192 = br_ba(8) * mt(32) * nt(32)
  int br_ba = bid & 7;                // XCD-local batch: 4MB working set fits per-XCD L2
  int tile = bid >> 3;
  int mt = tile >> 5;                 // D rows: fT tile (reused across consecutive blocks)
  int nt = tile & 31;                 // D cols: sT tile
  int t = threadIdx.x;
  int wid = t >> 6, l = t & 63, g = l >> 4, lr = l & 15;
  int wm = wid >> 1, wn = wid & 1;

  const unsigned short* fp = fT + ((size_t)br_ba * 4096 + mt * 128 + wm * 64) * 64;
  const unsigned short* sp = sT + ((size_t)br_ba * 4096 + nt * 128 + wn * 64) * 64;

  U16x8 afr[4][2], bfr[4][2];
  #pragma unroll
  for (int mf = 0; mf < 4; ++mf)
    #pragma unroll
    for (int kh = 0; kh < 2; ++kh)
      afr[mf][kh].q = *(const uint4*)(fp + (size_t)(mf * 16 + lr) * 64 + kh * 32 + g * 8);
  #pragma unroll
  for (int nf = 0; nf < 4; ++nf)
    #pragma unroll
    for (int kh = 0; kh < 2; ++kh)
      bfr[nf][kh].q = *(const uint4*)(sp + (size_t)(nf * 16 + lr) * 64 + kh * 32 + g * 8);

  f32x4 acc[4][4];
  #pragma unroll
  for (int mf = 0; mf < 4; ++mf)
    #pragma unroll
    for (int nf = 0; nf < 4; ++nf)
      acc[mf][nf] = (f32x4){0.f, 0.f, 0.f, 0.f};
  #pragma unroll
  for (int kh = 0; kh < 2; ++kh)
    #pragma unroll
    for (int mf = 0; mf < 4; ++mf)
      #pragma unroll
      for (int nf = 0; nf < 4; ++nf)
        acc[mf][nf] = __builtin_amdgcn_mfma_f32_16x16x32_bf16(
            afr[mf][kh].v, bfr[nf][kh].v, acc[mf][nf], 0, 0, 0);

  // Per-column-n stats over this block's 128 m rows.
  __shared__ float smx[2][128], ssm[2][128];
  #pragma unroll
  for (int nf = 0; nf < 4; ++nf) {
    float mx = -1e30f;
    #pragma unroll
    for (int mf = 0; mf < 4; ++mf)
      #pragma unroll
      for (int r = 0; r < 4; ++r)
        mx = fmaxf(mx, acc[mf][nf][r]);
    mx = fmaxf(mx, __shfl_xor(mx, 16));
    mx = fmaxf(mx, __shfl_xor(mx, 32));
    float sm = 0.f;
    #pragma unroll
    for (int mf = 0; mf < 4; ++mf)
      #pragma unroll
      for (int r = 0; r < 4; ++r)
        sm += __expf(acc[mf][nf][r] - mx);
    sm += __shfl_xor(sm, 16);
    sm += __shfl_xor(sm, 32);
    if (g == 0) {
      smx[wm][wn * 64 + nf * 16 + lr] = mx;
      ssm[wm][wn * 64 + nf * 16 + lr] = sm;
    }
  }
  __syncthreads();
  if (t < 128) {
    float m0 = smx[0][t], m1 = smx[1][t];
    float M = fmaxf(m0, m1);
    float S = ssm[0][t] * __expf(m0 - M) + ssm[1][t] * __expf(m1 - M);
    size_t idx = ((size_t)br_ba * 4096 + nt * 128 + t) * 32 + mt;
    stats_mx[idx] = M;
    stats_sm[idx] = S;
  }
}

// ---------------------------------------------------------------- K3: global max, row sums, Z per (br,ba)
__global__ __launch_bounds__(256) void k_combine(const float* stats_mx, const float* stats_sm,
                                                 float* roww, float* zs) {
  int br_ba = blockIdx.x;             // 8
  const float* mxp = stats_mx + (size_t)br_ba * 4096 * 32;
  const float* smp = stats_sm + (size_t)br_ba * 4096 * 32;
  int t = threadIdx.x;
  __shared__ float red[256];
  float mx = -1e30f;
  const float4* m4 = (const float4*)mxp;
  for (int i = t; i < 32768; i += 256) {
    float4 v = m4[i];
    mx = fmaxf(fmaxf(mx, fmaxf(v.x, v.y)), fmaxf(v.z, v.w));
  }
  red[t] = mx; __syncthreads();
  for (int s = 128; s > 0; s >>= 1) { if (t < s) red[t] = fmaxf(red[t], red[t + s]); __syncthreads(); }
  float gmax = red[0];
  __syncthreads();

  float zpart = 0.f;
  for (int k = 0; k < 16; ++k) {
    int n = k * 256 + t;
    const float4* rm = (const float4*)(mxp + (size_t)n * 32);
    const float4* rs = (const float4*)(smp + (size_t)n * 32);
    float acc = 0.f;
    #pragma unroll
    for (int q = 0; q < 8; ++q) {
      float4 mv = rm[q], sv = rs[q];
      acc += sv.x * __expf(mv.x - gmax);
      acc += sv.y * __expf(mv.y - gmax);
      acc += sv.z * __expf(mv.z - gmax);
      acc += sv.w * __expf(mv.w - gmax);
    }
    roww[br_ba * 4096 + n] = acc;
    zpart += acc;
  }
  red[t] = zpart; __syncthreads();
  for (int s = 128; s > 0; s >>= 1) { if (t < s) red[t] += red[t + s]; __syncthreads(); }
  if (t == 0) zs[br_ba] = red[0];
}

// ---------------------------------------------------------------- K4: gbar partials = sum_n w[n]*g[n][c]
__global__ __launch_bounds__(256) void k_gbar(const unsigned short* gT, const float* roww,
                                              float* gbar_part) {
  int bid = blockIdx.x;               // 128 = br_ba(8) * seg(16)
  int br_ba = bid & 7;
  int seg = bid >> 3;
  int t = threadIdx.x;
  int c = t & 63, part = t >> 6;
  const unsigned short* gp = gT + (size_t)br_ba * 4096 * 64;
  const float* wp = roww + br_ba * 4096;
  int n0 = seg * 256;
  float acc = 0.f;
  for (int n = n0 + part; n < n0 + 256; n += 4)
    acc += wp[n] * bf2f(gp[(size_t)n * 64 + c]);
  __shared__ float red[256];
  red[t] = acc; __syncthreads();
  if (t < 64)
    gbar_part[(size_t)(br_ba * 16 + seg) * 64 + c] =
        red[t] + red[t + 64] + red[t + 128] + red[t + 192];
}

// ---------------------------------------------------------------- K5: final loss
__global__ __launch_bounds__(256) void k_loss(const float* Sx, const float* gbar_part,
                                              const float* zs, const float* fsg_w, float* out) {
  int t = threadIdx.x;                // 256: ba = t>>6, d = t&63
  int ba = t >> 6, d = t & 63;
  __shared__ float gdiff[4][64];
  float gs = 0.f, gt = 0.f;
  #pragma unroll
  for (int seg = 0; seg < 16; ++seg) {
    gs += gbar_part[(size_t)((0 + ba) * 16 + seg) * 64 + d];
    gt += gbar_part[(size_t)((4 + ba) * 16 + seg) * 64 + d];
  }
  gdiff[ba][d] = gs / zs[ba] - gt / zs[4 + ba];
  __syncthreads();
  float dot = 0.f;
  for (int c = 0; c < 64; ++c) dot += fsg_w[d * 64 + c] * gdiff[ba][c];
  float sxd = Sx[(0 + ba) * 64 + d] - Sx[(4 + ba) * 64 + d];
  float diff = (sxd + dot) * (1.0f / 4096.0f);
  __shared__ float red[256];
  red[t] = diff * diff; __syncthreads();
  for (int s = 128; s > 0; s >>= 1) { if (t < s) red[t] += red[t + s]; __syncthreads(); }
  if (t == 0) {
    float lnon = red[0];
    out[0] = 2e-5f * lnon;            // NON*R*lnon   (= non_loss * B)
    out[1] = 2e-5f * lnon * 0.25f;    // non_loss
  }
}

// ----------------------------------------------------------------
extern "C" void kernel_launch(void* const* d_in, const int* in_sizes, int n_in,
                              void* d_out, int out_size, void* d_ws, size_t ws_size,
                              hipStream_t stream) {
  const float* stu   = (const float*)d_in[0];
  const float* tea   = (const float*)d_in[1];
  const float* si_w  = (const float*)d_in[2];
  const float* si_b  = (const float*)d_in[3];
  const float* fi_w  = (const float*)d_in[4];
  const float* fi_b  = (const float*)d_in[5];
  const float* gi_w  = (const float*)d_in[6];
  const float* gi_b  = (const float*)d_in[7];
  const float* fsg_w = (const float*)d_in[8];
  // fsg_b (d_in[9]) cancels in the stu-tea difference.

  char* ws = (char*)d_ws;
  size_t off = 0;
  auto alloc = [&](size_t bytes) -> void* {
    void* p = ws + off;
    off = (off + bytes + 255) & ~(size_t)255;
    return p;
  };
  unsigned short* wbs = (unsigned short*)alloc(4096 * 2);
  unsigned short* wbf = (unsigned short*)alloc(4096 * 2);
  unsigned short* wbg = (unsigned short*)alloc(4096 * 2);
  unsigned short* sT  = (unsigned short*)alloc((size_t)8 * 4096 * 64 * 2);
  unsigned short* fT  = (unsigned short*)alloc((size_t)8 * 4096 * 64 * 2);
  unsigned short* gT  = (unsigned short*)alloc((size_t)8 * 4096 * 64 * 2);
  float* stats_mx     = (float*)alloc((size_t)8 * 4096 * 32 * 4);
  float* stats_sm     = (float*)alloc((size_t)8 * 4096 * 32 * 4);
  float* Sx           = (float*)alloc(512 * 4);
  float* roww         = (float*)alloc((size_t)8 * 4096 * 4);
  float* zs           = (float*)alloc(8 * 4);
  float* gbar_part    = (float*)alloc((size_t)8 * 16 * 64 * 4);
  float* out          = (float*)d_out;

  k_prep_w<<<1, 256, 0, stream>>>(si_w, fi_w, gi_w, wbs, wbf, wbg);
  k_sx<<<512, 256, 0, stream>>>(stu, tea, Sx);
  k_proj<<<256, 256, 0, stream>>>(stu, tea, wbs, wbf, wbg, si_b, fi_b, gi_b, sT, fT, gT);
  k_scores<<<8192, 256, 0, stream>>>(sT, fT, stats_mx, stats_sm);
  k_combine<<<8, 256, 0, stream>>>(stats_mx, stats_sm, roww, zs);
  k_gbar<<<128, 256, 0, stream>>>(gT, roww, gbar_part);
  k_loss<<<1, 256, 0, stream>>>(Sx, gbar_part, zs, fsg_w, out);
}

// Round 2
// 103.242 us; speedup vs baseline: 1.5997x; 1.5997x over previous
//
#include <hip/hip_runtime.h>
#include <hip/hip_bf16.h>
#include <stdint.h>

typedef __bf16 bf16x8 __attribute__((ext_vector_type(8)));
typedef float  f32x4  __attribute__((ext_vector_type(4)));

union U16x8 { bf16x8 v; unsigned short s[8]; uint4 q; };

#define L2E 1.4426950408889634f

__device__ inline unsigned short f2bf(float f) {
  union { float f; unsigned int u; } x; x.f = f;
  unsigned int r = x.u + 0x7FFFu + ((x.u >> 16) & 1u);
  return (unsigned short)(r >> 16);
}
__device__ inline float bf2f(unsigned short u) {
  union { unsigned int u; float f; } x; x.u = ((unsigned int)u) << 16; return x.f;
}

// ---------------------------------------------------------------- Ksx: exact spatial sums of x
__global__ __launch_bounds__(256) void k_sx(const float* stu, const float* tea, float* Sx) {
  int bid = blockIdx.x;               // 512 = br(2) * ba(4) * c(64)
  int c = bid & 63, ba = (bid >> 6) & 3, br = bid >> 8;
  const float* xp = (br ? tea : stu) + (size_t)(ba * 64 + c) * 4096;
  int t = threadIdx.x;
  float acc = 0.f;
  const float4* p4 = (const float4*)xp;
  for (int i = t; i < 1024; i += 256) {
    float4 v = p4[i];
    acc += (v.x + v.y) + (v.z + v.w);
  }
  __shared__ float red[256];
  red[t] = acc; __syncthreads();
  for (int s = 128; s > 0; s >>= 1) { if (t < s) red[t] += red[t + s]; __syncthreads(); }
  if (t == 0) Sx[bid] = red[0];       // bid == (br*4+ba)*64 + c
}

// ---------------------------------------------------------------- K1: projections -> sT,fT,gT (bf16, [n][c])
__global__ __launch_bounds__(256) void k_proj(
    const float* stu, const float* tea,
    const float* si_w, const float* fi_w, const float* gi_w,
    const float* si_b, const float* fi_b, const float* gi_b,
    unsigned short* sT, unsigned short* fT, unsigned short* gT) {
  int bid = blockIdx.x;               // 256 = br_ba(8) * nt(32)
  int br_ba = bid & 7;
  int nt = bid >> 3;
  int br = br_ba >> 2, ba = br_ba & 3;
  const float* x = (br ? tea : stu) + (size_t)ba * 64 * 4096;
  int t = threadIdx.x;
  int wid = t >> 6, l = t & 63, g = l >> 4, lr = l & 15;
  int n0 = nt * 128 + wid * 32;

  // A fragments: rows n (output rows), k = channel c
  U16x8 afr[2][2];
  #pragma unroll
  for (int rf = 0; rf < 2; ++rf) {
    int n = n0 + rf * 16 + lr;
    #pragma unroll
    for (int kh = 0; kh < 2; ++kh) {
      #pragma unroll
      for (int j = 0; j < 8; ++j) {
        int c = kh * 32 + g * 8 + j;
        afr[rf][kh].s[j] = f2bf(x[(size_t)c * 4096 + n]);
      }
    }
  }

  size_t obase = (size_t)br_ba * 4096 * 64;
  auto proj_one = [&](const float* w, const float* bias, unsigned short* op) {
    U16x8 bfr[4][2];
    #pragma unroll
    for (int cf = 0; cf < 4; ++cf) {
      int d = cf * 16 + lr;
      #pragma unroll
      for (int kh = 0; kh < 2; ++kh) {
        const float* wr = w + d * 64 + kh * 32 + g * 8;
        float4 w0 = *(const float4*)(wr);
        float4 w1 = *(const float4*)(wr + 4);
        bfr[cf][kh].s[0] = f2bf(w0.x); bfr[cf][kh].s[1] = f2bf(w0.y);
        bfr[cf][kh].s[2] = f2bf(w0.z); bfr[cf][kh].s[3] = f2bf(w0.w);
        bfr[cf][kh].s[4] = f2bf(w1.x); bfr[cf][kh].s[5] = f2bf(w1.y);
        bfr[cf][kh].s[6] = f2bf(w1.z); bfr[cf][kh].s[7] = f2bf(w1.w);
      }
    }
    f32x4 acc[2][4];
    #pragma unroll
    for (int rf = 0; rf < 2; ++rf)
      #pragma unroll
      for (int cf = 0; cf < 4; ++cf)
        acc[rf][cf] = (f32x4){0.f, 0.f, 0.f, 0.f};
    #pragma unroll
    for (int kh = 0; kh < 2; ++kh)
      #pragma unroll
      for (int rf = 0; rf < 2; ++rf)
        #pragma unroll
        for (int cf = 0; cf < 4; ++cf)
          acc[rf][cf] = __builtin_amdgcn_mfma_f32_16x16x32_bf16(
              afr[rf][kh].v, bfr[cf][kh].v, acc[rf][cf], 0, 0, 0);
    #pragma unroll
    for (int cf = 0; cf < 4; ++cf) {
      float bias_v = bias[cf * 16 + lr];
      #pragma unroll
      for (int rf = 0; rf < 2; ++rf) {
        #pragma unroll
        for (int r = 0; r < 4; ++r) {
          int n = n0 + rf * 16 + g * 4 + r;
          op[(size_t)n * 64 + cf * 16 + lr] = f2bf(acc[rf][cf][r] + bias_v);
        }
      }
    }
  };
  proj_one(si_w, si_b, sT + obase);
  proj_one(fi_w, fi_b, fT + obase);
  proj_one(gi_w, gi_b, gT + obase);
}

// ---------------------------------------------------------------- K2: online column softmax stats (exp2 domain)
// Each wave owns 32 columns (n), streams its m-quarter in 64-row chunks.
// Per-thread running (M,S) per column: the 16x16 C layout puts a thread's 16
// values in ONE column -> no cross-lane ops until the final combine.
__global__ __launch_bounds__(256) void k_scores(
    const unsigned short* sT, const unsigned short* fT,
    float* stats_m, float* stats_s) {
  int bid = blockIdx.x;               // 1024 = br_ba(8) * strip(32) * mq(4)
  int br_ba = bid & 7;                // consecutive bids -> different XCDs, one br_ba per XCD
  int rest = bid >> 3;
  int strip = rest & 31;              // 128-column strip
  int mq = rest >> 5;                 // m-quarter (1024 rows)
  int t = threadIdx.x;
  int wid = t >> 6, l = t & 63, g = l >> 4, lr = l & 15;

  const unsigned short* sp = sT + ((size_t)br_ba * 4096 + strip * 128 + wid * 32) * 64;
  const unsigned short* fp = fT + ((size_t)br_ba * 4096 + mq * 1024) * 64;

  U16x8 bfr[2][2];
  #pragma unroll
  for (int nf = 0; nf < 2; ++nf)
    #pragma unroll
    for (int kh = 0; kh < 2; ++kh)
      bfr[nf][kh].q = *(const uint4*)(sp + (size_t)(nf * 16 + lr) * 64 + kh * 32 + g * 8);

  float M2[2] = {-1e30f, -1e30f};
  float S[2]  = {0.f, 0.f};

  for (int ch = 0; ch < 16; ++ch) {
    U16x8 afr[4][2];
    #pragma unroll
    for (int mf = 0; mf < 4; ++mf)
      #pragma unroll
      for (int kh = 0; kh < 2; ++kh)
        afr[mf][kh].q = *(const uint4*)(fp + (size_t)(ch * 64 + mf * 16 + lr) * 64 + kh * 32 + g * 8);

    f32x4 acc[4][2];
    #pragma unroll
    for (int mf = 0; mf < 4; ++mf)
      #pragma unroll
      for (int nf = 0; nf < 2; ++nf)
        acc[mf][nf] = (f32x4){0.f, 0.f, 0.f, 0.f};
    #pragma unroll
    for (int kh = 0; kh < 2; ++kh)
      #pragma unroll
      for (int mf = 0; mf < 4; ++mf)
        #pragma unroll
        for (int nf = 0; nf < 2; ++nf)
          acc[mf][nf] = __builtin_amdgcn_mfma_f32_16x16x32_bf16(
              afr[mf][kh].v, bfr[nf][kh].v, acc[mf][nf], 0, 0, 0);

    #pragma unroll
    for (int nf = 0; nf < 2; ++nf) {
      float v[16];
      #pragma unroll
      for (int mf = 0; mf < 4; ++mf)
        #pragma unroll
        for (int r = 0; r < 4; ++r)
          v[mf * 4 + r] = acc[mf][nf][r];
      // explicit max tree (depth 4)
      float m[16];
      #pragma unroll
      for (int i = 0; i < 16; ++i) m[i] = v[i];
      #pragma unroll
      for (int st = 8; st > 0; st >>= 1)
        #pragma unroll
        for (int i = 0; i < 8; ++i)
          if (i < st) m[i] = fmaxf(m[i], m[i + st]);
      float nm = fmaxf(M2[nf], m[0] * L2E);
      // exp2 in scaled domain: exp(x - M) == exp2(x*log2e - M2)
      float e[16];
      #pragma unroll
      for (int i = 0; i < 16; ++i)
        e[i] = exp2f(fmaf(v[i], L2E, -nm));
      #pragma unroll
      for (int st = 8; st > 0; st >>= 1)
        #pragma unroll
        for (int i = 0; i < 8; ++i)
          if (i < st) e[i] += e[i + st];
      S[nf] = S[nf] * exp2f(M2[nf] - nm) + e[0];
      M2[nf] = nm;
    }
  }

  // combine across the 4 g-groups (they hold different row-quarters of the same column)
  #pragma unroll
  for (int nf = 0; nf < 2; ++nf) {
    #pragma unroll
    for (int sh = 16; sh <= 32; sh <<= 1) {
      float Mo = __shfl_xor(M2[nf], sh);
      float So = __shfl_xor(S[nf], sh);
      float nm = fmaxf(M2[nf], Mo);
      S[nf] = S[nf] * exp2f(M2[nf] - nm) + So * exp2f(Mo - nm);
      M2[nf] = nm;
    }
  }
  if (g == 0) {
    #pragma unroll
    for (int nf = 0; nf < 2; ++nf) {
      int col = strip * 128 + wid * 32 + nf * 16 + lr;
      size_t idx = ((size_t)br_ba * 4096 + col) * 4 + mq;
      stats_m[idx] = M2[nf];
      stats_s[idx] = S[nf];
    }
  }
}

// ---------------------------------------------------------------- K3: global max per (br,ba) over 16K stats
__global__ __launch_bounds__(256) void k_gmax(const float* stats_m, float* gmaxs) {
  int br_ba = blockIdx.x;             // 8
  int t = threadIdx.x;
  const float4* p = (const float4*)(stats_m + (size_t)br_ba * 4096 * 4);
  float mx = -1e30f;
  for (int i = t; i < 4096; i += 256) {
    float4 v = p[i];
    mx = fmaxf(fmaxf(mx, fmaxf(v.x, v.y)), fmaxf(v.z, v.w));
  }
  __shared__ float red[256];
  red[t] = mx; __syncthreads();
  for (int s = 128; s > 0; s >>= 1) { if (t < s) red[t] = fmaxf(red[t], red[t + s]); __syncthreads(); }
  if (t == 0) gmaxs[br_ba] = red[0];
}

// ---------------------------------------------------------------- K4: row weights inline + gbar partials + Z partials
__global__ __launch_bounds__(256) void k_gbar(const unsigned short* gT,
                                              const float* stats_m, const float* stats_s,
                                              const float* gmaxs,
                                              float* gbar_part, float* zpart) {
  int bid = blockIdx.x;               // 128 = br_ba(8) * seg(16)
  int br_ba = bid & 7;
  int seg = bid >> 3;
  int t = threadIdx.x;
  float gmax = gmaxs[br_ba];
  int n0 = seg * 256;

  __shared__ float wlds[256];
  {
    int n = n0 + t;
    float4 mv = *(const float4*)(stats_m + ((size_t)br_ba * 4096 + n) * 4);
    float4 sv = *(const float4*)(stats_s + ((size_t)br_ba * 4096 + n) * 4);
    float w = sv.x * exp2f(mv.x - gmax) + sv.y * exp2f(mv.y - gmax)
            + sv.z * exp2f(mv.z - gmax) + sv.w * exp2f(mv.w - gmax);
    wlds[t] = w;
  }
  __syncthreads();

  // Z partial for this segment
  __shared__ float red[256];
  red[t] = wlds[t]; __syncthreads();
  for (int s = 128; s > 0; s >>= 1) { if (t < s) red[t] += red[t + s]; __syncthreads(); }
  if (t == 0) zpart[br_ba * 16 + seg] = red[0];
  __syncthreads();

  // gbar partial: sum_n w[n] * g[n][c]
  int c = t & 63, part = t >> 6;
  const unsigned short* gp = gT + (size_t)br_ba * 4096 * 64;
  float acc = 0.f;
  for (int k = part; k < 256; k += 4)
    acc += wlds[k] * bf2f(gp[(size_t)(n0 + k) * 64 + c]);
  red[t] = acc; __syncthreads();
  if (t < 64)
    gbar_part[(size_t)(br_ba * 16 + seg) * 64 + c] =
        red[t] + red[t + 64] + red[t + 128] + red[t + 192];
}

// ---------------------------------------------------------------- K5: final loss
__global__ __launch_bounds__(256) void k_loss(const float* Sx, const float* gbar_part,
                                              const float* zpart, const float* fsg_w, float* out) {
  int t = threadIdx.x;                // 256: ba = t>>6, d = t&63
  int ba = t >> 6, d = t & 63;
  __shared__ float gdiff[4][64];
  float gs = 0.f, gt_ = 0.f, zs_s = 0.f, zs_t = 0.f;
  #pragma unroll
  for (int seg = 0; seg < 16; ++seg) {
    gs   += gbar_part[(size_t)((0 + ba) * 16 + seg) * 64 + d];
    gt_  += gbar_part[(size_t)((4 + ba) * 16 + seg) * 64 + d];
    zs_s += zpart[(0 + ba) * 16 + seg];
    zs_t += zpart[(4 + ba) * 16 + seg];
  }
  gdiff[ba][d] = gs / zs_s - gt_ / zs_t;
  __syncthreads();
  float dot = 0.f;
  for (int c = 0; c < 64; ++c) dot += fsg_w[d * 64 + c] * gdiff[ba][c];
  float sxd = Sx[(0 + ba) * 64 + d] - Sx[(4 + ba) * 64 + d];
  float diff = (sxd + dot) * (1.0f / 4096.0f);
  __shared__ float red[256];
  red[t] = diff * diff; __syncthreads();
  for (int s = 128; s > 0; s >>= 1) { if (t < s) red[t] += red[t + s]; __syncthreads(); }
  if (t == 0) {
    float lnon = red[0];
    out[0] = 2e-5f * lnon;            // NON*R*lnon   (= non_loss * B)
    out[1] = 2e-5f * lnon * 0.25f;    // non_loss
  }
}

// ----------------------------------------------------------------
extern "C" void kernel_launch(void* const* d_in, const int* in_sizes, int n_in,
                              void* d_out, int out_size, void* d_ws, size_t ws_size,
                              hipStream_t stream) {
  const float* stu   = (const float*)d_in[0];
  const float* tea   = (const float*)d_in[1];
  const float* si_w  = (const float*)d_in[2];
  const float* si_b  = (const float*)d_in[3];
  const float* fi_w  = (const float*)d_in[4];
  const float* fi_b  = (const float*)d_in[5];
  const float* gi_w  = (const float*)d_in[6];
  const float* gi_b  = (const float*)d_in[7];
  const float* fsg_w = (const float*)d_in[8];
  // fsg_b (d_in[9]) cancels in the stu-tea difference.

  char* ws = (char*)d_ws;
  size_t off = 0;
  auto alloc = [&](size_t bytes) -> void* {
    void* p = ws + off;
    off = (off + bytes + 255) & ~(size_t)255;
    return p;
  };
  unsigned short* sT  = (unsigned short*)alloc((size_t)8 * 4096 * 64 * 2);
  unsigned short* fT  = (unsigned short*)alloc((size_t)8 * 4096 * 64 * 2);
  unsigned short* gT  = (unsigned short*)alloc((size_t)8 * 4096 * 64 * 2);
  float* stats_m      = (float*)alloc((size_t)8 * 4096 * 4 * 4);
  float* stats_s      = (float*)alloc((size_t)8 * 4096 * 4 * 4);
  float* Sx           = (float*)alloc(512 * 4);
  float* gmaxs        = (float*)alloc(8 * 4);
  float* zpart        = (float*)alloc(128 * 4);
  float* gbar_part    = (float*)alloc((size_t)8 * 16 * 64 * 4);
  float* out          = (float*)d_out;

  k_sx<<<512, 256, 0, stream>>>(stu, tea, Sx);
  k_proj<<<256, 256, 0, stream>>>(stu, tea, si_w, fi_w, gi_w, si_b, fi_b, gi_b, sT, fT, gT);
  k_scores<<<1024, 256, 0, stream>>>(sT, fT, stats_m, stats_s);
  k_gmax<<<8, 256, 0, stream>>>(stats_m, gmaxs);
  k_gbar<<<128, 256, 0, stream>>>(gT, stats_m, stats_s, gmaxs, gbar_part, zpart);
  k_loss<<<1, 256, 0, stream>>>(Sx, gbar_part, zpart, fsg_w, out);
}